// Round 1
// baseline (166.798 us; speedup 1.0000x reference)
//
#include <hip/hip_runtime.h>
#include <hip/hip_bf16.h>

// Causal attention, B=2 NH=16 T=2048 D=64, fp32 I/O, bf16 MFMA flash-attention.
// Layouts per cdna_hip_programming.md §3 (m89/m120-verified):
//   mfma_f32_16x16x32_bf16: A[m=lane&15][k=(lane>>4)*8+j], B[k=(lane>>4)*8+j][n=lane&15],
//   C/D: col=lane&15, row=(lane>>4)*4+reg.

typedef __bf16 bf16;
typedef __bf16 bf16x8 __attribute__((ext_vector_type(8)));
typedef float floatx4 __attribute__((ext_vector_type(4)));

#define T_SEQ 2048
#define DH 64
#define TQ 64
#define TK 64
#define NQT (T_SEQ / TQ)   // 32
#define BHN 32             // B*NH
#define KSTR 72            // LDS row stride (bf16 elems): 144 B, 16B-aligned, odd-ish banks

__global__ __launch_bounds__(256, 2)
void fa_fwd(const float* __restrict__ Qg, const float* __restrict__ Kg,
            const float* __restrict__ Vg, float* __restrict__ Og)
{
    __shared__ __align__(16) bf16 Ks[TK * KSTR];        // K tile, row-major [key][dim]
    __shared__ __align__(16) bf16 Vt[DH * KSTR];        // V tile, transposed [dim][key]
    __shared__ __align__(16) bf16 Ps[4 * 16 * KSTR];    // per-wave P tile [qrow][key]

    const int gid = (int)blockIdx.x;
    const int bh  = gid & (BHN - 1);
    const int qt  = (NQT - 1) - (gid >> 5);   // heavy q-tiles dispatch first
    const int q0  = qt * TQ;

    const size_t base = (size_t)bh * T_SEQ * DH;
    const float* Qb = Qg + base;
    const float* Kb = Kg + base;
    const float* Vb = Vg + base;
    float*       Ob = Og + base;

    const int tid  = (int)threadIdx.x;
    const int wave = tid >> 6;
    const int lane = tid & 63;
    const int quad = lane >> 4;
    const int l16  = lane & 15;

    // ---- Q tile as MFMA A-fragments, kept in registers for the whole kernel ----
    bf16x8 qa[2];
    {
        const int qrow = q0 + wave * 16 + l16;
        #pragma unroll
        for (int kk = 0; kk < 2; ++kk) {
            const float* s = Qb + (size_t)qrow * DH + kk * 32 + quad * 8;
            float4 f0 = *(const float4*)(s);
            float4 f1 = *(const float4*)(s + 4);
            bf16x8 t;
            t[0] = (bf16)f0.x; t[1] = (bf16)f0.y; t[2] = (bf16)f0.z; t[3] = (bf16)f0.w;
            t[4] = (bf16)f1.x; t[5] = (bf16)f1.y; t[6] = (bf16)f1.z; t[7] = (bf16)f1.w;
            qa[kk] = t;
        }
    }

    floatx4 oacc[4];
    #pragma unroll
    for (int dt = 0; dt < 4; ++dt) oacc[dt] = (floatx4){0.f, 0.f, 0.f, 0.f};
    float m_run[4], l_run[4];
    #pragma unroll
    for (int r = 0; r < 4; ++r) { m_run[r] = -INFINITY; l_run[r] = 0.f; }

    const float cexp = 0.18033688011112042f;  // (1/sqrt(64)) * log2(e)

    const int sr = tid >> 2;          // staging row   0..63
    const int sc = (tid & 3) * 16;    // staging col chunk {0,16,32,48}

    for (int kt = 0; kt <= qt; ++kt) {
        const int k0 = kt * TK;

        __syncthreads();   // protect Ks/Vt reads of previous iteration
        {   // ---- stage K (bf16 row-major) and V (bf16 transposed) ----
            const float* ks = Kb + (size_t)(k0 + sr) * DH + sc;
            float ktmp[16];
            *(float4*)(ktmp + 0)  = *(const float4*)(ks + 0);
            *(float4*)(ktmp + 4)  = *(const float4*)(ks + 4);
            *(float4*)(ktmp + 8)  = *(const float4*)(ks + 8);
            *(float4*)(ktmp + 12) = *(const float4*)(ks + 12);
            bf16x8 p0, p1;
            #pragma unroll
            for (int j = 0; j < 8; ++j) { p0[j] = (bf16)ktmp[j]; p1[j] = (bf16)ktmp[8 + j]; }
            *(bf16x8*)&Ks[sr * KSTR + sc + 0] = p0;
            *(bf16x8*)&Ks[sr * KSTR + sc + 8] = p1;

            const float* vs = Vb + (size_t)(k0 + sr) * DH + sc;
            float vtmp[16];
            *(float4*)(vtmp + 0)  = *(const float4*)(vs + 0);
            *(float4*)(vtmp + 4)  = *(const float4*)(vs + 4);
            *(float4*)(vtmp + 8)  = *(const float4*)(vs + 8);
            *(float4*)(vtmp + 12) = *(const float4*)(vs + 12);
            #pragma unroll
            for (int j = 0; j < 16; ++j) Vt[(sc + j) * KSTR + sr] = (bf16)vtmp[j];
        }
        __syncthreads();

        // ---- S = Q · K^T (raw scores; scale folded into exp2) ----
        floatx4 sacc[4];
        #pragma unroll
        for (int nt = 0; nt < 4; ++nt) sacc[nt] = (floatx4){0.f, 0.f, 0.f, 0.f};
        #pragma unroll
        for (int nt = 0; nt < 4; ++nt) {
            #pragma unroll
            for (int kk = 0; kk < 2; ++kk) {
                bf16x8 b = *(const bf16x8*)&Ks[(nt * 16 + l16) * KSTR + kk * 32 + quad * 8];
                sacc[nt] = __builtin_amdgcn_mfma_f32_16x16x32_bf16(qa[kk], b, sacc[nt], 0, 0, 0);
            }
        }

        // ---- causal mask (diagonal tile only; q0 == k0 there) ----
        if (kt == qt) {
            #pragma unroll
            for (int nt = 0; nt < 4; ++nt) {
                const int ng = nt * 16 + l16;
                #pragma unroll
                for (int r = 0; r < 4; ++r) {
                    const int mg = wave * 16 + quad * 4 + r;
                    if (ng > mg) sacc[nt][r] = -INFINITY;
                }
            }
        }

        // ---- online softmax: row stats live on 16 consecutive lanes (same quad) ----
        float mt[4];
        #pragma unroll
        for (int r = 0; r < 4; ++r) {
            float v = fmaxf(fmaxf(sacc[0][r], sacc[1][r]), fmaxf(sacc[2][r], sacc[3][r]));
            #pragma unroll
            for (int msk = 1; msk <= 8; msk <<= 1) v = fmaxf(v, __shfl_xor(v, msk));
            mt[r] = v;
        }
        float alpha[4], rs[4];
        #pragma unroll
        for (int r = 0; r < 4; ++r) {
            const float mn = fmaxf(m_run[r], mt[r]);
            alpha[r] = __builtin_amdgcn_exp2f(cexp * (m_run[r] - mn));  // 0 on first tile
            m_run[r] = mn;
            rs[r] = 0.f;
        }

        bf16* Pw = &Ps[wave * 16 * KSTR];
        #pragma unroll
        for (int nt = 0; nt < 4; ++nt) {
            #pragma unroll
            for (int r = 0; r < 4; ++r) {
                const float p = __builtin_amdgcn_exp2f(cexp * (sacc[nt][r] - m_run[r]));
                rs[r] += p;
                Pw[(quad * 4 + r) * KSTR + nt * 16 + l16] = (bf16)p;   // C-layout → LDS
            }
        }
        #pragma unroll
        for (int r = 0; r < 4; ++r) {
            float v = rs[r];
            #pragma unroll
            for (int msk = 1; msk <= 8; msk <<= 1) v += __shfl_xor(v, msk);
            l_run[r] = l_run[r] * alpha[r] + v;
        }
        #pragma unroll
        for (int dt = 0; dt < 4; ++dt) {
            #pragma unroll
            for (int r = 0; r < 4; ++r) oacc[dt][r] *= alpha[r];
        }

        // ---- O += P · V  (P re-read in A-layout; per-wave buffer, wave-in-order LDS) ----
        bf16x8 pa[2];
        #pragma unroll
        for (int kk = 0; kk < 2; ++kk)
            pa[kk] = *(const bf16x8*)&Pw[l16 * KSTR + kk * 32 + quad * 8];
        #pragma unroll
        for (int dt = 0; dt < 4; ++dt) {
            #pragma unroll
            for (int kk = 0; kk < 2; ++kk) {
                bf16x8 vb = *(const bf16x8*)&Vt[(dt * 16 + l16) * KSTR + kk * 32 + quad * 8];
                oacc[dt] = __builtin_amdgcn_mfma_f32_16x16x32_bf16(pa[kk], vb, oacc[dt], 0, 0, 0);
            }
        }
    }

    // ---- epilogue: O / l, C-layout scatter (64B-coalesced per quad) ----
    #pragma unroll
    for (int dt = 0; dt < 4; ++dt) {
        #pragma unroll
        for (int r = 0; r < 4; ++r) {
            const int row = q0 + wave * 16 + quad * 4 + r;
            Ob[(size_t)row * DH + dt * 16 + l16] = oacc[dt][r] / l_run[r];
        }
    }
}

extern "C" void kernel_launch(void* const* d_in, const int* in_sizes, int n_in,
                              void* d_out, int out_size, void* d_ws, size_t ws_size,
                              hipStream_t stream) {
    const float* Q = (const float*)d_in[0];
    const float* K = (const float*)d_in[1];
    const float* V = (const float*)d_in[2];
    float* O = (float*)d_out;
    (void)in_sizes; (void)n_in; (void)out_size; (void)d_ws; (void)ws_size;
    fa_fwd<<<dim3(BHN * NQT), dim3(256), 0, stream>>>(Q, K, V, O);
}

// Round 2
// 134.130 us; speedup vs baseline: 1.2436x; 1.2436x over previous
//
#include <hip/hip_runtime.h>
#include <hip/hip_bf16.h>

// Causal attention, B=2 NH=16 T=2048 D=64, fp32 I/O.
// R2: prepass (K->bf16, V->bf16 transposed) + global_load_lds staging into
// XOR-swizzled LDS + double buffer + no-max online softmax (partial denominators).

typedef __bf16 bf16;
typedef __bf16 bf16x8 __attribute__((ext_vector_type(8)));
typedef float floatx4 __attribute__((ext_vector_type(4)));

#define T_SEQ 2048
#define DH 64
#define TQ 64
#define TK 64
#define NQT (T_SEQ / TQ)   // 32
#define BHN 32             // B*NH
#define CEXP 0.18033688011112042f  // (1/sqrt(64)) * log2(e)

__device__ __forceinline__ void gload16(const bf16* g, bf16* l) {
    __builtin_amdgcn_global_load_lds(
        (const __attribute__((address_space(1))) void*)g,
        (__attribute__((address_space(3))) void*)l, 16, 0, 0);
}

// ---------------- prepass: K fp32 -> bf16 (same layout) ----------------
__global__ __launch_bounds__(256) void cvt_k(const float* __restrict__ in,
                                             bf16* __restrict__ out) {
    const int i = ((int)blockIdx.x * 256 + (int)threadIdx.x) * 8;
    float4 a = *(const float4*)(in + i);
    float4 b = *(const float4*)(in + i + 4);
    bf16x8 o;
    o[0] = (bf16)a.x; o[1] = (bf16)a.y; o[2] = (bf16)a.z; o[3] = (bf16)a.w;
    o[4] = (bf16)b.x; o[5] = (bf16)b.y; o[6] = (bf16)b.z; o[7] = (bf16)b.w;
    *(bf16x8*)(out + i) = o;
}

// ---------------- prepass: V [bh][T][64] fp32 -> V^T [bh][64][T] bf16 ----------------
__global__ __launch_bounds__(256) void transpose_v(const float* __restrict__ V,
                                                   bf16* __restrict__ Vt) {
    __shared__ bf16 tile[64][72];
    const int bh = (int)blockIdx.x & (BHN - 1);
    const int t0 = ((int)blockIdx.x >> 5) * 64;
    const int tid = (int)threadIdx.x;
    {
        const int r = tid >> 2;              // key row 0..63
        const int c = (tid & 3) * 16;        // dim col chunk
        const float* s = V + ((size_t)(bh * T_SEQ) + t0 + r) * DH + c;
        float4 f0 = *(const float4*)(s + 0);
        float4 f1 = *(const float4*)(s + 4);
        float4 f2 = *(const float4*)(s + 8);
        float4 f3 = *(const float4*)(s + 12);
        bf16x8 p0, p1;
        p0[0] = (bf16)f0.x; p0[1] = (bf16)f0.y; p0[2] = (bf16)f0.z; p0[3] = (bf16)f0.w;
        p0[4] = (bf16)f1.x; p0[5] = (bf16)f1.y; p0[6] = (bf16)f1.z; p0[7] = (bf16)f1.w;
        p1[0] = (bf16)f2.x; p1[1] = (bf16)f2.y; p1[2] = (bf16)f2.z; p1[3] = (bf16)f2.w;
        p1[4] = (bf16)f3.x; p1[5] = (bf16)f3.y; p1[6] = (bf16)f3.z; p1[7] = (bf16)f3.w;
        *(bf16x8*)&tile[r][c + 0] = p0;
        *(bf16x8*)&tile[r][c + 8] = p1;
    }
    __syncthreads();
    {
        const int d  = tid & 63;             // dim 0..63
        const int k0 = (tid >> 6) * 16;      // key chunk
        bf16x8 o0, o1;
        #pragma unroll
        for (int j = 0; j < 8; ++j) { o0[j] = tile[k0 + j][d]; o1[j] = tile[k0 + 8 + j][d]; }
        bf16* o = Vt + ((size_t)bh * DH + d) * T_SEQ + t0 + k0;
        *(bf16x8*)(o + 0) = o0;
        *(bf16x8*)(o + 8) = o1;
    }
}

// ---------------- main flash kernel ----------------
// LDS swizzle: tile row = 8 chunks of 16B; slot chunk i of row r holds global
// chunk i^(r&7). Staging lane l -> row r0+(l>>3), slot chunk l&7, so the
// global chunk it must fetch is (l&7)^(r&7) — contiguous per 8 lanes.
__global__ __launch_bounds__(256, 4)
void fa_fwd(const float* __restrict__ Qg, const bf16* __restrict__ Kb,
            const bf16* __restrict__ Vt, float* __restrict__ Og)
{
    __shared__ __align__(16) bf16 Ksh[2][TK * DH];    // 8 KB x2, swizzled [key][dim]
    __shared__ __align__(16) bf16 Vsh[2][DH * TK];    // 8 KB x2, swizzled [dim][key]
    __shared__ __align__(16) bf16 Psh[4][16 * TK];    // 2 KB per wave, swizzled [qrow][key]

    const int gid  = (int)blockIdx.x;
    const int bh   = gid & (BHN - 1);
    const int qt   = (NQT - 1) - (gid >> 5);   // heavy q-tiles first
    const int q0   = qt * TQ;

    const int tid  = (int)threadIdx.x;
    const int wave = tid >> 6;
    const int lane = tid & 63;
    const int quad = lane >> 4;
    const int l16  = lane & 15;
    const int rl   = lane >> 3;   // staging: row-in-group 0..7
    const int ch   = lane & 7;    // staging: slot chunk
    const int gch  = ch ^ rl;     // staging: global chunk ((r&7)==rl)

    const float* Qb  = Qg + ((size_t)bh * T_SEQ + q0) * DH;
    const bf16*  Kbh = Kb + (size_t)bh * T_SEQ * DH;
    const bf16*  Vbh = Vt + (size_t)bh * DH * T_SEQ;
    float*       Ob  = Og + ((size_t)bh * T_SEQ + q0) * DH;

    // Q tile as A-fragments (A[m=l16][k=quad*8+j]), fp32->bf16 once
    bf16x8 qa[2];
    {
        const float* s0 = Qb + (size_t)(wave * 16 + l16) * DH + quad * 8;
        #pragma unroll
        for (int kk = 0; kk < 2; ++kk) {
            const float* s = s0 + kk * 32;
            float4 f0 = *(const float4*)(s);
            float4 f1 = *(const float4*)(s + 4);
            bf16x8 t;
            t[0] = (bf16)f0.x; t[1] = (bf16)f0.y; t[2] = (bf16)f0.z; t[3] = (bf16)f0.w;
            t[4] = (bf16)f1.x; t[5] = (bf16)f1.y; t[6] = (bf16)f1.z; t[7] = (bf16)f1.w;
            qa[kk] = t;
        }
    }

    floatx4 oacc[4];
    #pragma unroll
    for (int dt = 0; dt < 4; ++dt) oacc[dt] = (floatx4){0.f, 0.f, 0.f, 0.f};
    float l_part[4] = {0.f, 0.f, 0.f, 0.f};

    // ---- staging: 2 instrs K + 2 instrs V^T per wave per tile ----
    auto stage = [&](int kt, int buf) {
        const bf16* kg = Kbh + (size_t)kt * TK * DH;
        const bf16* vg = Vbh + kt * TK;
        #pragma unroll
        for (int g = 0; g < 2; ++g) {
            const int row = wave * 16 + g * 8;   // tile row base (key for K, dim for V^T)
            gload16(kg + (size_t)(row + rl) * DH + gch * 8, &Ksh[buf][row * DH]);
            gload16(vg + (size_t)(row + rl) * T_SEQ + gch * 8, &Vsh[buf][row * TK]);
        }
    };

    stage(0, 0);
    __syncthreads();

    for (int kt = 0; kt <= qt; ++kt) {
        const int buf = kt & 1;
        if (kt < qt) stage(kt + 1, buf ^ 1);   // in flight across the compute phase

        // ---- S = Q K^T ----
        floatx4 sacc[4];
        #pragma unroll
        for (int nt = 0; nt < 4; ++nt) sacc[nt] = (floatx4){0.f, 0.f, 0.f, 0.f};
        #pragma unroll
        for (int nt = 0; nt < 4; ++nt) {
            const int R = nt * 16 + l16;
            #pragma unroll
            for (int kk = 0; kk < 2; ++kk) {
                bf16x8 b = *(const bf16x8*)&Ksh[buf][R * DH + (((kk * 4 + quad) ^ (l16 & 7)) * 8)];
                sacc[nt] = __builtin_amdgcn_mfma_f32_16x16x32_bf16(qa[kk], b, sacc[nt], 0, 0, 0);
            }
        }

        // ---- causal mask on the diagonal tile ----
        if (kt == qt) {
            #pragma unroll
            for (int nt = 0; nt < 4; ++nt) {
                const int ng = nt * 16 + l16;
                #pragma unroll
                for (int r = 0; r < 4; ++r) {
                    const int mg = wave * 16 + quad * 4 + r;
                    if (ng > mg) sacc[nt][r] = -INFINITY;
                }
            }
        }

        // ---- p = exp2(cexp*s); partial denominator per lane; P -> LDS (swizzled) ----
        bf16* Pw = Psh[wave];
        #pragma unroll
        for (int nt = 0; nt < 4; ++nt) {
            const int key = nt * 16 + l16;
            #pragma unroll
            for (int r = 0; r < 4; ++r) {
                const float p = __builtin_amdgcn_exp2f(CEXP * sacc[nt][r]);
                l_part[r] += p;
                const int qrow = quad * 4 + r;
                Pw[qrow * TK + (((key >> 3) ^ (qrow & 7)) * 8 + (key & 7))] = (bf16)p;
            }
        }

        // ---- P fragments (same-wave LDS round trip, in-order DS pipe) ----
        bf16x8 pa[2];
        #pragma unroll
        for (int kk = 0; kk < 2; ++kk)
            pa[kk] = *(const bf16x8*)&Pw[l16 * TK + (((kk * 4 + quad) ^ (l16 & 7)) * 8)];

        // ---- O += P V ----
        #pragma unroll
        for (int dt = 0; dt < 4; ++dt) {
            const int R = dt * 16 + l16;
            #pragma unroll
            for (int kk = 0; kk < 2; ++kk) {
                bf16x8 vb = *(const bf16x8*)&Vsh[buf][R * TK + (((kk * 4 + quad) ^ (l16 & 7)) * 8)];
                oacc[dt] = __builtin_amdgcn_mfma_f32_16x16x32_bf16(pa[kk], vb, oacc[dt], 0, 0, 0);
            }
        }

        __syncthreads();   // drains this iter's prefetch; releases buf^1 for overwrite
    }

    // ---- one denominator reduction for the whole kernel ----
    float inv_l[4];
    #pragma unroll
    for (int r = 0; r < 4; ++r) {
        float v = l_part[r];
        #pragma unroll
        for (int msk = 1; msk <= 8; msk <<= 1) v += __shfl_xor(v, msk);
        inv_l[r] = 1.0f / v;
    }

    #pragma unroll
    for (int dt = 0; dt < 4; ++dt) {
        #pragma unroll
        for (int r = 0; r < 4; ++r) {
            const int row = wave * 16 + quad * 4 + r;
            Ob[(size_t)row * DH + dt * 16 + l16] = oacc[dt][r] * inv_l[r];
        }
    }
}

extern "C" void kernel_launch(void* const* d_in, const int* in_sizes, int n_in,
                              void* d_out, int out_size, void* d_ws, size_t ws_size,
                              hipStream_t stream) {
    const float* Q = (const float*)d_in[0];
    const float* K = (const float*)d_in[1];
    const float* V = (const float*)d_in[2];
    float* O = (float*)d_out;
    (void)in_sizes; (void)n_in; (void)out_size; (void)ws_size;

    const size_t nelem = (size_t)BHN * T_SEQ * DH;   // 4,194,304
    bf16* Kbf = (bf16*)d_ws;                          // 8 MiB
    bf16* Vtb = Kbf + nelem;                          // 8 MiB

    cvt_k<<<dim3((unsigned)(nelem / (256 * 8))), dim3(256), 0, stream>>>(K, Kbf);
    transpose_v<<<dim3(BHN * (T_SEQ / 64)), dim3(256), 0, stream>>>(V, Vtb);
    fa_fwd<<<dim3(BHN * NQT), dim3(256), 0, stream>>>(Q, Kbf, Vtb, O);
}